// Round 2
// baseline (3538.294 us; speedup 1.0000x reference)
//
#include <hip/hip_runtime.h>
#include <hip/hip_bf16.h>
#include <math.h>

#define LRELU_SLOPE 0.2f
typedef __hip_bfloat16 bf16;
typedef __hip_bfloat162 bf16x2;

__device__ __forceinline__ float lrelu(float v) { return v > 0.f ? v : LRELU_SLOPE * v; }

__device__ __forceinline__ float ldf(const float* p) { return *p; }
__device__ __forceinline__ float ldf(const bf16* p) { return __bfloat162float(*p); }

__device__ __forceinline__ void st2(bf16* p, float x, float y) {
  float2 f{x, y};
  *(bf16x2*)p = __float22bfloat162_rn(f);
}
__device__ __forceinline__ void st2(float* p, float x, float y) {
  *(float2*)p = float2{x, y};
}

// ---------------- zero helper (avoid hipMemsetAsync in capture) ----------------

__global__ void k_zero(unsigned int* __restrict__ p, long n) {
  long i = (long)blockIdx.x * blockDim.x + threadIdx.x;
  if (i < n) p[i] = 0u;
}

// ---------------- preprocessing: counting-sort edges by dst ----------------

__global__ void k_hist(const int* __restrict__ dst, int* __restrict__ deg, int E, int Et) {
  int e = blockIdx.x * blockDim.x + threadIdx.x;
  if (e >= Et) return;
  int d = (e < E) ? dst[e] : (e - E);   // self-loops appended
  atomicAdd(&deg[d], 1);
}

__global__ void k_scan1(const int* __restrict__ deg, int* __restrict__ offs,
                        int* __restrict__ bsum, int n) {
  __shared__ int sd[256];
  int t = threadIdx.x;
  int base = blockIdx.x * 1024 + t * 4;
  int v[4]; int tsum = 0;
#pragma unroll
  for (int i = 0; i < 4; ++i) { v[i] = (base + i < n) ? deg[base + i] : 0; tsum += v[i]; }
  sd[t] = tsum;
  __syncthreads();
  for (int off = 1; off < 256; off <<= 1) {
    int x = (t >= off) ? sd[t - off] : 0;
    __syncthreads();
    sd[t] += x;
    __syncthreads();
  }
  int excl = sd[t] - tsum;
#pragma unroll
  for (int i = 0; i < 4; ++i) { if (base + i < n) offs[base + i] = excl; excl += v[i]; }
  if (t == 255) bsum[blockIdx.x] = sd[255];
}

__global__ void k_scan2(int* bsum, int nb) {
  if (threadIdx.x == 0 && blockIdx.x == 0) {
    int run = 0;
    for (int i = 0; i < nb; ++i) { int t = bsum[i]; bsum[i] = run; run += t; }
  }
}

__global__ void k_scan3(int* __restrict__ offs, const int* __restrict__ bsum, int n, int total) {
  int t = threadIdx.x;
  int base = blockIdx.x * 1024 + t * 4;
  int add = bsum[blockIdx.x];
#pragma unroll
  for (int i = 0; i < 4; ++i) if (base + i < n) offs[base + i] += add;
  if (blockIdx.x == 0 && t == 0) offs[n] = total;
}

__global__ void k_scatter(const int* __restrict__ src, const int* __restrict__ dst,
                          const int* __restrict__ offs, int* __restrict__ cur,
                          int* __restrict__ ssrc, int E, int Et) {
  int e = blockIdx.x * blockDim.x + threadIdx.x;
  if (e >= Et) return;
  int s, d;
  if (e < E) { s = src[e]; d = dst[e]; } else { s = d = e - E; }
  int pos = offs[d] + atomicAdd(&cur[d], 1);
  ssrc[pos] = s;
}

// ---------------- tiled GEMM: C[M,NN](bf16) = A[M,K] @ B[K,NN](f32) ----------------
// M % 64 == 0 (200000 = 64*3125), K % 16 == 0, NN % 64 == 0.

struct bf16x4 { bf16 a, b, c, d; };

template <typename AT>
__global__ __launch_bounds__(256) void k_gemm(const AT* __restrict__ A,
                                              const float* __restrict__ B,
                                              bf16* __restrict__ C,
                                              int K, int NN) {
  __shared__ float As[16][68];
  __shared__ float Bs[16][64];
  int t = threadIdx.x;
  int tx = t & 15, ty = t >> 4;
  const AT* Ab = A + (size_t)blockIdx.x * 64 * K;
  const float* Bb = B + blockIdx.y * 64;
  float acc[4][4] = {};
  for (int kb = 0; kb < K; kb += 16) {
#pragma unroll
    for (int i = 0; i < 4; ++i) {
      int l = t + 256 * i;
      As[l & 15][l >> 4] = ldf(&Ab[(size_t)(l >> 4) * K + kb + (l & 15)]);
    }
#pragma unroll
    for (int i = 0; i < 4; ++i) {
      int l = t + 256 * i;
      Bs[l >> 6][l & 63] = Bb[(size_t)(kb + (l >> 6)) * NN + (l & 63)];
    }
    __syncthreads();
#pragma unroll
    for (int kk = 0; kk < 16; ++kk) {
      float4 av = *(const float4*)&As[kk][ty * 4];
      float4 bv = *(const float4*)&Bs[kk][tx * 4];
      float a[4] = {av.x, av.y, av.z, av.w};
      float b[4] = {bv.x, bv.y, bv.z, bv.w};
#pragma unroll
      for (int i = 0; i < 4; ++i)
#pragma unroll
        for (int j = 0; j < 4; ++j) acc[i][j] += a[i] * b[j];
    }
    __syncthreads();
  }
#pragma unroll
  for (int i = 0; i < 4; ++i) {
    bf16x4 o = {__float2bfloat16(acc[i][0]), __float2bfloat16(acc[i][1]),
                __float2bfloat16(acc[i][2]), __float2bfloat16(acc[i][3])};
    *(bf16x4*)&C[(size_t)(blockIdx.x * 64 + ty * 4 + i) * NN + blockIdx.y * 64 + tx * 4] = o;
  }
}

// ---------------- attention logits al_s/al_d: one wave per node ----------------

__global__ void k_al(const bf16* __restrict__ h, const float* __restrict__ as,
                     const float* __restrict__ ad, float* __restrict__ al_s,
                     float* __restrict__ al_d, int N, int H, int F) {
  int wave = (blockIdx.x * blockDim.x + threadIdx.x) >> 6;
  int lane = threadIdx.x & 63;
  if (wave >= N) return;
  const bf16* hrow = h + (size_t)wave * H * F;
  for (int hd = 0; hd < H; ++hd) {
    float ss = 0.f, sd = 0.f;
    for (int f = lane; f < F; f += 64) {
      float v = __bfloat162float(hrow[hd * F + f]);
      ss += v * as[hd * F + f];
      sd += v * ad[hd * F + f];
    }
#pragma unroll
    for (int off = 32; off; off >>= 1) {
      ss += __shfl_xor(ss, off, 64);
      sd += __shfl_xor(sd, off, 64);
    }
    if (lane == 0) { al_s[wave * H + hd] = ss; al_d[wave * H + hd] = sd; }
  }
}

// ---------------- segment softmax (max + expsum): one wave per node ----------------

__global__ void k_attn(const int* __restrict__ ssrc, const int* __restrict__ offs,
                       const float* __restrict__ al_s, const float* __restrict__ al_d,
                       float* __restrict__ alpha, float* __restrict__ rden, int N, int H) {
  int wave = (blockIdx.x * blockDim.x + threadIdx.x) >> 6;
  int lane = threadIdx.x & 63;
  if (wave >= N) return;
  int start = offs[wave], end = offs[wave + 1];
  float ald[3], mx[3], den[3];
  for (int hd = 0; hd < H; ++hd) { ald[hd] = al_d[wave * H + hd]; mx[hd] = -1e30f; den[hd] = 0.f; }
  for (int pos = start + lane; pos < end; pos += 64) {
    int s = ssrc[pos];
    for (int hd = 0; hd < H; ++hd) {
      float e = lrelu(al_s[s * H + hd] + ald[hd]);
      mx[hd] = fmaxf(mx[hd], e);
    }
  }
  for (int hd = 0; hd < H; ++hd)
#pragma unroll
    for (int off = 32; off; off >>= 1) mx[hd] = fmaxf(mx[hd], __shfl_xor(mx[hd], off, 64));
  for (int pos = start + lane; pos < end; pos += 64) {
    int s = ssrc[pos];
    for (int hd = 0; hd < H; ++hd) {
      float e = lrelu(al_s[s * H + hd] + ald[hd]);
      float ex = __expf(e - mx[hd]);
      alpha[pos * H + hd] = ex;
      den[hd] += ex;
    }
  }
  for (int hd = 0; hd < H; ++hd) {
#pragma unroll
    for (int off = 32; off; off >>= 1) den[hd] += __shfl_xor(den[hd], off, 64);
    if (lane == 0) rden[wave * H + hd] = 1.f / (den[hd] + 1e-16f);
  }
}

// ---------------- weighted aggregation: one wave per (node, head) ----------------
// F == 128: lane holds features (lane*2, lane*2+1)

template <typename OT>
__global__ void k_agg(const bf16* __restrict__ hbuf, const int* __restrict__ ssrc,
                      const int* __restrict__ offs, const float* __restrict__ alpha,
                      const float* __restrict__ rden, const float* __restrict__ bias,
                      OT* __restrict__ out, int N, int H) {
  int gw = (blockIdx.x * blockDim.x + threadIdx.x) >> 6;
  int lane = threadIdx.x & 63;
  if (gw >= N * H) return;
  int n = gw / H, hd = gw - n * H;
  int start = offs[n], end = offs[n + 1];
  float r = rden[n * H + hd];
  int f0 = lane * 2;
  float ax = 0.f, ay = 0.f;
  for (int pos = start; pos < end; ++pos) {
    int s = ssrc[pos];
    float a = alpha[pos * H + hd] * r;
    bf16x2 v = *(const bf16x2*)&hbuf[((size_t)s * H + hd) * 128 + f0];
    float2 vf = __bfloat1622float2(v);
    ax += a * vf.x;
    ay += a * vf.y;
  }
  float ox = lrelu(ax + bias[hd * 128 + f0]);
  float oy = lrelu(ay + bias[hd * 128 + f0 + 1]);
  st2(&out[((size_t)n * H + hd) * 128 + f0], ox, oy);
}

// ---------------- global mean pool (layer-3 out is fp32) ----------------

__global__ void k_pool_acc(const float* __restrict__ h, const int* __restrict__ batch,
                           float* __restrict__ pool, int* __restrict__ cnt, int N) {
  int n = blockIdx.x;
  int t = threadIdx.x;   // 128 threads = feature
  if (n >= N) return;
  int g = batch[n];
  atomicAdd(&pool[g * 128 + t], h[(size_t)n * 128 + t]);
  if (t == 0) atomicAdd(&cnt[g], 1);
}

__global__ void k_pool_div(const float* __restrict__ pool, const int* __restrict__ cnt,
                           float* __restrict__ out, int G) {
  int i = blockIdx.x * blockDim.x + threadIdx.x;
  if (i >= G * 128) return;
  int g = i >> 7;
  float c = (float)max(cnt[g], 1);
  out[i] = pool[i] / c;
}

__global__ void k_zero_out(float* __restrict__ out, int n) {
  int i = blockIdx.x * blockDim.x + threadIdx.x;
  if (i < n) out[i] = 0.f;
}

// ---------------- host launcher ----------------

extern "C" void kernel_launch(void* const* d_in, const int* in_sizes, int n_in,
                              void* d_out, int out_size, void* d_ws, size_t ws_size,
                              hipStream_t stream) {
  const float* x   = (const float*)d_in[0];
  const int*   ei  = (const int*)d_in[1];
  const int*   bat = (const int*)d_in[2];
  const float* W1  = (const float*)d_in[3];
  const float* a1s = (const float*)d_in[4];
  const float* a1d = (const float*)d_in[5];
  const float* b1  = (const float*)d_in[6];
  const float* W2  = (const float*)d_in[7];
  const float* a2s = (const float*)d_in[8];
  const float* a2d = (const float*)d_in[9];
  const float* b2  = (const float*)d_in[10];
  const float* W3  = (const float*)d_in[11];
  const float* a3s = (const float*)d_in[12];
  const float* a3d = (const float*)d_in[13];
  const float* b3  = (const float*)d_in[14];
  float* out = (float*)d_out;

  const int N = in_sizes[2];          // 200000
  const int E = in_sizes[1] / 2;      // 1600000
  const int Et = E + N;               // with self-loops
  const int G = out_size / 128;       // 5000
  const int H = 3;

  // ---- workspace carve (bf16 intermediates) ----
  char* p = (char*)d_ws;
  auto carve = [&](size_t bytes) { void* r = (void*)p; p += (bytes + 255) & ~(size_t)255; return r; };
  bf16*  bufA   = (bf16*)carve((size_t)N * 384 * 2);   // agg output / GEMM input (layer3 out fp32 fits: N*128*4 < N*384*2)
  bf16*  bufB   = (bf16*)carve((size_t)N * 384 * 2);   // GEMM output h
  float* al_s   = (float*)carve((size_t)N * 3 * 4);
  float* al_d   = (float*)carve((size_t)N * 3 * 4);
  float* rden   = (float*)carve((size_t)N * 3 * 4);
  float* alpha  = (float*)carve((size_t)Et * 3 * 4);
  int*   ssrc   = (int*)carve((size_t)Et * 4);
  int*   offs   = (int*)carve((size_t)(N + 1) * 4);
  int*   deg    = (int*)carve((size_t)N * 4);
  int*   cur    = (int*)carve((size_t)N * 4);
  int*   bsum   = (int*)carve(4096 * 4);
  float* pool   = (float*)carve((size_t)G * 128 * 4);
  int*   cnt    = (int*)carve((size_t)G * 4);
  size_t need = (size_t)(p - (char*)d_ws);

  if (ws_size < need) {
    // diagnostic fallback: clean absmax failure instead of a memory fault
    k_zero_out<<<(out_size + 255) / 256, 256, 0, stream>>>(out, out_size);
    return;
  }

  const int* esrc = ei;
  const int* edst = ei + E;

  int ebl = (Et + 255) / 256;
  int NB = (N + 1023) / 1024;
  int nodeWaveBlocks = (N * 64 + 255) / 256;

  // ---- sort edges by dst ----
  k_zero<<<(N + 255) / 256, 256, 0, stream>>>((unsigned int*)deg, N);
  k_hist<<<ebl, 256, 0, stream>>>(edst, deg, E, Et);
  k_scan1<<<NB, 256, 0, stream>>>(deg, offs, bsum, N);
  k_scan2<<<1, 64, 0, stream>>>(bsum, NB);
  k_scan3<<<NB, 256, 0, stream>>>(offs, bsum, N, Et);
  k_zero<<<(N + 255) / 256, 256, 0, stream>>>((unsigned int*)cur, N);
  k_scatter<<<ebl, 256, 0, stream>>>(esrc, edst, offs, cur, ssrc, E, Et);

  dim3 g6(N / 64, 6), g2(N / 64, 2);

  // ---- layer 1: x[N,128] @ W1[128,384] ----
  k_gemm<float><<<g6, 256, 0, stream>>>(x, W1, bufB, 128, 384);
  k_al<<<nodeWaveBlocks, 256, 0, stream>>>(bufB, a1s, a1d, al_s, al_d, N, H, 128);
  k_attn<<<nodeWaveBlocks, 256, 0, stream>>>(ssrc, offs, al_s, al_d, alpha, rden, N, H);
  k_agg<bf16><<<(N * H * 64 + 255) / 256, 256, 0, stream>>>(bufB, ssrc, offs, alpha, rden, b1, bufA, N, H);

  // ---- layer 2: bufA[N,384] @ W2[384,384] ----
  k_gemm<bf16><<<g6, 256, 0, stream>>>(bufA, W2, bufB, 384, 384);
  k_al<<<nodeWaveBlocks, 256, 0, stream>>>(bufB, a2s, a2d, al_s, al_d, N, H, 128);
  k_attn<<<nodeWaveBlocks, 256, 0, stream>>>(ssrc, offs, al_s, al_d, alpha, rden, N, H);
  k_agg<bf16><<<(N * H * 64 + 255) / 256, 256, 0, stream>>>(bufB, ssrc, offs, alpha, rden, b2, bufA, N, H);

  // ---- layer 3: bufA[N,384] @ W3[384,128], heads=1, fp32 output ----
  k_gemm<bf16><<<g2, 256, 0, stream>>>(bufA, W3, bufB, 384, 128);
  k_al<<<nodeWaveBlocks, 256, 0, stream>>>(bufB, a3s, a3d, al_s, al_d, N, 1, 128);
  k_attn<<<nodeWaveBlocks, 256, 0, stream>>>(ssrc, offs, al_s, al_d, alpha, rden, N, 1);
  float* out3 = (float*)bufA;
  k_agg<float><<<(N * 64 + 255) / 256, 256, 0, stream>>>(bufB, ssrc, offs, alpha, rden, b3, out3, N, 1);

  // ---- global mean pool ----
  k_zero<<<(G * 128 + 255) / 256, 256, 0, stream>>>((unsigned int*)pool, (long)G * 128);
  k_zero<<<(G + 255) / 256, 256, 0, stream>>>((unsigned int*)cnt, G);
  k_pool_acc<<<N, 128, 0, stream>>>(out3, bat, pool, cnt, N);
  k_pool_div<<<(G * 128 + 255) / 256, 256, 0, stream>>>(pool, cnt, out, G);
}

// Round 3
// 2731.480 us; speedup vs baseline: 1.2954x; 1.2954x over previous
//
#include <hip/hip_runtime.h>
#include <hip/hip_bf16.h>
#include <math.h>

#define LRELU_SLOPE 0.2f
typedef __hip_bfloat16 bf16;
typedef __hip_bfloat162 bf16x2;

typedef short s8v __attribute__((ext_vector_type(8)));   // 8 bf16 (4 VGPRs)
typedef float f4v __attribute__((ext_vector_type(4)));   // MFMA acc

__device__ __forceinline__ float lrelu(float v) { return v > 0.f ? v : LRELU_SLOPE * v; }

__device__ __forceinline__ void st2(bf16* p, float x, float y) {
  float2 f{x, y};
  *(bf16x2*)p = __float22bfloat162_rn(f);
}
__device__ __forceinline__ void st2(float* p, float x, float y) {
  *(float2*)p = float2{x, y};
}

// ---------------- zero helper (avoid hipMemsetAsync in capture) ----------------

__global__ void k_zero(unsigned int* __restrict__ p, long n) {
  long i = (long)blockIdx.x * blockDim.x + threadIdx.x;
  if (i < n) p[i] = 0u;
}

__global__ void k_zero_out(float* __restrict__ out, int n) {
  int i = blockIdx.x * blockDim.x + threadIdx.x;
  if (i < n) out[i] = 0.f;
}

// ---------------- dtype prep: x -> bf16, W -> bf16 transposed ----------------

__global__ void k_cvt(const float* __restrict__ x, bf16* __restrict__ xb, long n) {
  long i = (long)blockIdx.x * blockDim.x + threadIdx.x;
  if (i < n) xb[i] = __float2bfloat16(x[i]);
}

// W[K][NN] (f32) -> Wt[NN][K] (bf16)
__global__ void k_tw(const float* __restrict__ W, bf16* __restrict__ Wt, int K, int NN) {
  int i = blockIdx.x * blockDim.x + threadIdx.x;
  if (i >= K * NN) return;
  int k = i / NN, n = i - k * NN;
  Wt[(size_t)n * K + k] = __float2bfloat16(W[i]);
}

// ---------------- preprocessing: counting-sort edges by dst ----------------

__global__ void k_hist(const int* __restrict__ dst, int* __restrict__ deg, int E, int Et) {
  int e = blockIdx.x * blockDim.x + threadIdx.x;
  if (e >= Et) return;
  int d = (e < E) ? dst[e] : (e - E);   // self-loops appended
  atomicAdd(&deg[d], 1);
}

__global__ void k_scan1(const int* __restrict__ deg, int* __restrict__ offs,
                        int* __restrict__ bsum, int n) {
  __shared__ int sd[256];
  int t = threadIdx.x;
  int base = blockIdx.x * 1024 + t * 4;
  int v[4]; int tsum = 0;
#pragma unroll
  for (int i = 0; i < 4; ++i) { v[i] = (base + i < n) ? deg[base + i] : 0; tsum += v[i]; }
  sd[t] = tsum;
  __syncthreads();
  for (int off = 1; off < 256; off <<= 1) {
    int x = (t >= off) ? sd[t - off] : 0;
    __syncthreads();
    sd[t] += x;
    __syncthreads();
  }
  int excl = sd[t] - tsum;
#pragma unroll
  for (int i = 0; i < 4; ++i) { if (base + i < n) offs[base + i] = excl; excl += v[i]; }
  if (t == 255) bsum[blockIdx.x] = sd[255];
}

__global__ void k_scan2(int* bsum, int nb) {
  if (threadIdx.x == 0 && blockIdx.x == 0) {
    int run = 0;
    for (int i = 0; i < nb; ++i) { int t = bsum[i]; bsum[i] = run; run += t; }
  }
}

__global__ void k_scan3(int* __restrict__ offs, const int* __restrict__ bsum, int n, int total) {
  int t = threadIdx.x;
  int base = blockIdx.x * 1024 + t * 4;
  int add = bsum[blockIdx.x];
#pragma unroll
  for (int i = 0; i < 4; ++i) if (base + i < n) offs[base + i] += add;
  if (blockIdx.x == 0 && t == 0) offs[n] = total;
}

__global__ void k_scatter(const int* __restrict__ src, const int* __restrict__ dst,
                          const int* __restrict__ offs, int* __restrict__ cur,
                          int* __restrict__ ssrc, int E, int Et) {
  int e = blockIdx.x * blockDim.x + threadIdx.x;
  if (e >= Et) return;
  int s, d;
  if (e < E) { s = src[e]; d = dst[e]; } else { s = d = e - E; }
  int pos = offs[d] + atomicAdd(&cur[d], 1);
  ssrc[pos] = s;
}

// ---------------- bf16 MFMA GEMM: C[M,NN](bf16) = A[M,K](bf16) @ Wt[NN,K](bf16)^T ----
// M%64==0, K%64==0, NN%64==0. Block 256 thr = 4 waves; 64x64 tile; wave w -> cols w*16..+16.
// A staged in LDS with XOR swizzle (chunk ^= row&7): global_load_lds-compatible layout,
// ds_read_b128 readers see <=2 lanes/bank (free per m136).

__global__ __launch_bounds__(256) void k_gemm_mfma(const bf16* __restrict__ A,
                                                   const bf16* __restrict__ Wt,
                                                   bf16* __restrict__ C,
                                                   int K, int NN) {
  __shared__ __align__(16) short sA[64 * 64];   // 8 KB, 64 rows x 64 cols bf16
  int t = threadIdx.x;
  int wv = t >> 6, lane = t & 63;
  int quad = lane >> 4, l15 = lane & 15;
  size_t bm0 = (size_t)blockIdx.x * 64;
  int bn0 = blockIdx.y * 64;
  const bf16* Ab = A + bm0 * K;
  const bf16* Bp = Wt + (size_t)(bn0 + wv * 16 + l15) * K;  // this lane's weight row
  f4v acc[4] = {f4v{0,0,0,0}, f4v{0,0,0,0}, f4v{0,0,0,0}, f4v{0,0,0,0}};

  for (int kb = 0; kb < K; kb += 64) {
#pragma unroll
    for (int j = 0; j < 2; ++j) {
      int idx = j * 256 + t;
      int row = idx >> 3, p = idx & 7;
      int c = p ^ (row & 7);                  // global 16B-chunk landing at pos p
      const bf16* g = Ab + (size_t)row * K + kb + c * 8;
      __builtin_amdgcn_global_load_lds(
          (const __attribute__((address_space(1))) void*)g,
          (__attribute__((address_space(3))) void*)((char*)sA + (size_t)(j * 256 + wv * 64) * 16),
          16, 0, 0);
    }
    __syncthreads();
#pragma unroll
    for (int kk = 0; kk < 2; ++kk) {
      s8v bfrag = *(const s8v*)(Bp + kb + kk * 32 + quad * 8);
#pragma unroll
      for (int ms = 0; ms < 4; ++ms) {
        int row = ms * 16 + l15;
        int pos = (kk * 4 + quad) ^ (row & 7);
        s8v afrag = *(const s8v*)((const char*)sA + (size_t)row * 128 + pos * 16);
        acc[ms] = __builtin_amdgcn_mfma_f32_16x16x32_bf16(afrag, bfrag, acc[ms], 0, 0, 0);
      }
    }
    __syncthreads();
  }
  // C/D layout: col = lane&15, row = quad*4 + reg  [m89/m91 verified]
  int coln = bn0 + wv * 16 + l15;
#pragma unroll
  for (int ms = 0; ms < 4; ++ms)
#pragma unroll
    for (int r = 0; r < 4; ++r)
      C[(bm0 + ms * 16 + quad * 4 + r) * NN + coln] = __float2bfloat16(acc[ms][r]);
}

// ---------------- attention logits al_s/al_d: one wave per node ----------------

__global__ void k_al(const bf16* __restrict__ h, const float* __restrict__ as,
                     const float* __restrict__ ad, float* __restrict__ al_s,
                     float* __restrict__ al_d, int N, int H, int F) {
  int wave = (blockIdx.x * blockDim.x + threadIdx.x) >> 6;
  int lane = threadIdx.x & 63;
  if (wave >= N) return;
  const bf16* hrow = h + (size_t)wave * H * F;
  for (int hd = 0; hd < H; ++hd) {
    float ss = 0.f, sd = 0.f;
    for (int f = lane; f < F; f += 64) {
      float v = __bfloat162float(hrow[hd * F + f]);
      ss += v * as[hd * F + f];
      sd += v * ad[hd * F + f];
    }
#pragma unroll
    for (int off = 32; off; off >>= 1) {
      ss += __shfl_xor(ss, off, 64);
      sd += __shfl_xor(sd, off, 64);
    }
    if (lane == 0) { al_s[wave * H + hd] = ss; al_d[wave * H + hd] = sd; }
  }
}

// ---------------- segment softmax (max + expsum): one wave per node ----------------

__global__ void k_attn(const int* __restrict__ ssrc, const int* __restrict__ offs,
                       const float* __restrict__ al_s, const float* __restrict__ al_d,
                       float* __restrict__ alpha, float* __restrict__ rden, int N, int H) {
  int wave = (blockIdx.x * blockDim.x + threadIdx.x) >> 6;
  int lane = threadIdx.x & 63;
  if (wave >= N) return;
  int start = offs[wave], end = offs[wave + 1];
  float ald[3], mx[3], den[3];
  for (int hd = 0; hd < H; ++hd) { ald[hd] = al_d[wave * H + hd]; mx[hd] = -1e30f; den[hd] = 0.f; }
  for (int pos = start + lane; pos < end; pos += 64) {
    int s = ssrc[pos];
    for (int hd = 0; hd < H; ++hd) {
      float e = lrelu(al_s[s * H + hd] + ald[hd]);
      mx[hd] = fmaxf(mx[hd], e);
    }
  }
  for (int hd = 0; hd < H; ++hd)
#pragma unroll
    for (int off = 32; off; off >>= 1) mx[hd] = fmaxf(mx[hd], __shfl_xor(mx[hd], off, 64));
  for (int pos = start + lane; pos < end; pos += 64) {
    int s = ssrc[pos];
    for (int hd = 0; hd < H; ++hd) {
      float e = lrelu(al_s[s * H + hd] + ald[hd]);
      float ex = __expf(e - mx[hd]);
      alpha[pos * H + hd] = ex;
      den[hd] += ex;
    }
  }
  for (int hd = 0; hd < H; ++hd) {
#pragma unroll
    for (int off = 32; off; off >>= 1) den[hd] += __shfl_xor(den[hd], off, 64);
    if (lane == 0) rden[wave * H + hd] = 1.f / (den[hd] + 1e-16f);
  }
}

// ---------------- weighted aggregation: one wave per (node, head) ----------------

template <typename OT>
__global__ void k_agg(const bf16* __restrict__ hbuf, const int* __restrict__ ssrc,
                      const int* __restrict__ offs, const float* __restrict__ alpha,
                      const float* __restrict__ rden, const float* __restrict__ bias,
                      OT* __restrict__ out, int N, int H) {
  int gw = (blockIdx.x * blockDim.x + threadIdx.x) >> 6;
  int lane = threadIdx.x & 63;
  if (gw >= N * H) return;
  int n = gw / H, hd = gw - n * H;
  int start = offs[n], end = offs[n + 1];
  float r = rden[n * H + hd];
  int f0 = lane * 2;
  float ax = 0.f, ay = 0.f;
  for (int pos = start; pos < end; ++pos) {
    int s = ssrc[pos];
    float a = alpha[pos * H + hd] * r;
    bf16x2 v = *(const bf16x2*)&hbuf[((size_t)s * H + hd) * 128 + f0];
    float2 vf = __bfloat1622float2(v);
    ax += a * vf.x;
    ay += a * vf.y;
  }
  float ox = lrelu(ax + bias[hd * 128 + f0]);
  float oy = lrelu(ay + bias[hd * 128 + f0 + 1]);
  st2(&out[((size_t)n * H + hd) * 128 + f0], ox, oy);
}

// ---------------- global mean pool (layer-3 out is fp32) ----------------

__global__ void k_pool_acc(const float* __restrict__ h, const int* __restrict__ batch,
                           float* __restrict__ pool, int* __restrict__ cnt, int N) {
  int n = blockIdx.x;
  int t = threadIdx.x;   // 128 threads = feature
  if (n >= N) return;
  int g = batch[n];
  atomicAdd(&pool[g * 128 + t], h[(size_t)n * 128 + t]);
  if (t == 0) atomicAdd(&cnt[g], 1);
}

__global__ void k_pool_div(const float* __restrict__ pool, const int* __restrict__ cnt,
                           float* __restrict__ out, int G) {
  int i = blockIdx.x * blockDim.x + threadIdx.x;
  if (i >= G * 128) return;
  int g = i >> 7;
  float c = (float)max(cnt[g], 1);
  out[i] = pool[i] / c;
}

// ---------------- host launcher ----------------

extern "C" void kernel_launch(void* const* d_in, const int* in_sizes, int n_in,
                              void* d_out, int out_size, void* d_ws, size_t ws_size,
                              hipStream_t stream) {
  const float* x   = (const float*)d_in[0];
  const int*   ei  = (const int*)d_in[1];
  const int*   bat = (const int*)d_in[2];
  const float* W1  = (const float*)d_in[3];
  const float* a1s = (const float*)d_in[4];
  const float* a1d = (const float*)d_in[5];
  const float* b1  = (const float*)d_in[6];
  const float* W2  = (const float*)d_in[7];
  const float* a2s = (const float*)d_in[8];
  const float* a2d = (const float*)d_in[9];
  const float* b2  = (const float*)d_in[10];
  const float* W3  = (const float*)d_in[11];
  const float* a3s = (const float*)d_in[12];
  const float* a3d = (const float*)d_in[13];
  const float* b3  = (const float*)d_in[14];
  float* out = (float*)d_out;

  const int N = in_sizes[2];          // 200000
  const int E = in_sizes[1] / 2;      // 1600000
  const int Et = E + N;               // with self-loops
  const int G = out_size / 128;       // 5000
  const int H = 3;

  // ---- workspace carve (bf16 intermediates) ----
  char* p = (char*)d_ws;
  auto carve = [&](size_t bytes) { void* r = (void*)p; p += (bytes + 255) & ~(size_t)255; return r; };
  bf16*  bufA   = (bf16*)carve((size_t)N * 384 * 2);   // agg out / GEMM A; also hosts xb & fp32 layer-3 out
  bf16*  bufB   = (bf16*)carve((size_t)N * 384 * 2);   // GEMM output h
  float* al_s   = (float*)carve((size_t)N * 3 * 4);
  float* al_d   = (float*)carve((size_t)N * 3 * 4);
  float* rden   = (float*)carve((size_t)N * 3 * 4);
  float* alpha  = (float*)carve((size_t)Et * 3 * 4);
  int*   ssrc   = (int*)carve((size_t)Et * 4);
  int*   offs   = (int*)carve((size_t)(N + 1) * 4);
  int*   deg    = (int*)carve((size_t)N * 4);
  int*   cur    = (int*)carve((size_t)N * 4);
  int*   bsum   = (int*)carve(4096 * 4);
  float* pool   = (float*)carve((size_t)G * 128 * 4);
  int*   cnt    = (int*)carve((size_t)G * 4);
  bf16*  Wt1    = (bf16*)carve((size_t)384 * 128 * 2);
  bf16*  Wt2    = (bf16*)carve((size_t)384 * 384 * 2);
  bf16*  Wt3    = (bf16*)carve((size_t)128 * 384 * 2);
  size_t need = (size_t)(p - (char*)d_ws);

  if (ws_size < need) {
    k_zero_out<<<(out_size + 255) / 256, 256, 0, stream>>>(out, out_size);
    return;
  }

  const int* esrc = ei;
  const int* edst = ei + E;

  int ebl = (Et + 255) / 256;
  int NB = (N + 1023) / 1024;
  int nodeWaveBlocks = (N * 64 + 255) / 256;

  // ---- prep: weight transpose+cast, x cast (xb aliases bufA) ----
  bf16* xb = bufA;
  k_cvt<<<((long)N * 128 + 255) / 256, 256, 0, stream>>>(x, xb, (long)N * 128);
  k_tw<<<(128 * 384 + 255) / 256, 256, 0, stream>>>(W1, Wt1, 128, 384);
  k_tw<<<(384 * 384 + 255) / 256, 256, 0, stream>>>(W2, Wt2, 384, 384);
  k_tw<<<(384 * 128 + 255) / 256, 256, 0, stream>>>(W3, Wt3, 384, 128);

  // ---- sort edges by dst ----
  k_zero<<<(N + 255) / 256, 256, 0, stream>>>((unsigned int*)deg, N);
  k_hist<<<ebl, 256, 0, stream>>>(edst, deg, E, Et);
  k_scan1<<<NB, 256, 0, stream>>>(deg, offs, bsum, N);
  k_scan2<<<1, 64, 0, stream>>>(bsum, NB);
  k_scan3<<<NB, 256, 0, stream>>>(offs, bsum, N, Et);
  k_zero<<<(N + 255) / 256, 256, 0, stream>>>((unsigned int*)cur, N);
  k_scatter<<<ebl, 256, 0, stream>>>(esrc, edst, offs, cur, ssrc, E, Et);

  dim3 g1(N / 64, 6), g2(N / 64, 6), g3(N / 64, 2);

  // ---- layer 1: xb[N,128] @ W1 -> bufB[N,384] ----
  k_gemm_mfma<<<g1, 256, 0, stream>>>(xb, Wt1, bufB, 128, 384);
  k_al<<<nodeWaveBlocks, 256, 0, stream>>>(bufB, a1s, a1d, al_s, al_d, N, H, 128);
  k_attn<<<nodeWaveBlocks, 256, 0, stream>>>(ssrc, offs, al_s, al_d, alpha, rden, N, H);
  k_agg<bf16><<<(N * H * 64 + 255) / 256, 256, 0, stream>>>(bufB, ssrc, offs, alpha, rden, b1, bufA, N, H);

  // ---- layer 2: bufA[N,384] @ W2 -> bufB[N,384] ----
  k_gemm_mfma<<<g2, 256, 0, stream>>>(bufA, Wt2, bufB, 384, 384);
  k_al<<<nodeWaveBlocks, 256, 0, stream>>>(bufB, a2s, a2d, al_s, al_d, N, H, 128);
  k_attn<<<nodeWaveBlocks, 256, 0, stream>>>(ssrc, offs, al_s, al_d, alpha, rden, N, H);
  k_agg<bf16><<<(N * H * 64 + 255) / 256, 256, 0, stream>>>(bufB, ssrc, offs, alpha, rden, b2, bufA, N, H);

  // ---- layer 3: bufA[N,384] @ W3 -> bufB[N,128], heads=1, fp32 agg out ----
  k_gemm_mfma<<<g3, 256, 0, stream>>>(bufA, Wt3, bufB, 384, 128);
  k_al<<<nodeWaveBlocks, 256, 0, stream>>>(bufB, a3s, a3d, al_s, al_d, N, 1, 128);
  k_attn<<<nodeWaveBlocks, 256, 0, stream>>>(ssrc, offs, al_s, al_d, alpha, rden, N, 1);
  float* out3 = (float*)bufA;
  k_agg<float><<<(N * 64 + 255) / 256, 256, 0, stream>>>(bufB, ssrc, offs, alpha, rden, b3, out3, N, 1);

  // ---- global mean pool ----
  k_zero<<<(G * 128 + 255) / 256, 256, 0, stream>>>((unsigned int*)pool, (long)G * 128);
  k_zero<<<(G + 255) / 256, 256, 0, stream>>>((unsigned int*)cnt, G);
  k_pool_acc<<<N, 128, 0, stream>>>(out3, bat, pool, cnt, N);
  k_pool_div<<<(G * 128 + 255) / 256, 256, 0, stream>>>(pool, cnt, out, G);
}

// Round 4
// 2093.474 us; speedup vs baseline: 1.6902x; 1.3048x over previous
//
#include <hip/hip_runtime.h>
#include <hip/hip_bf16.h>
#include <math.h>

#define LRELU_SLOPE 0.2f
typedef __hip_bfloat16 bf16;
typedef __hip_bfloat162 bf16x2;

typedef short s8v __attribute__((ext_vector_type(8)));   // 8 bf16 (4 VGPRs)
typedef float f4v __attribute__((ext_vector_type(4)));   // MFMA acc

__device__ __forceinline__ float lrelu(float v) { return v > 0.f ? v : LRELU_SLOPE * v; }

__device__ __forceinline__ void st2(bf16* p, float x, float y) {
  float2 f{x, y};
  *(bf16x2*)p = __float22bfloat162_rn(f);
}
__device__ __forceinline__ void st2(float* p, float x, float y) {
  *(float2*)p = float2{x, y};
}

// ---------------- zero helper (avoid hipMemsetAsync in capture) ----------------

__global__ void k_zero(unsigned int* __restrict__ p, long n) {
  long i = (long)blockIdx.x * blockDim.x + threadIdx.x;
  if (i < n) p[i] = 0u;
}

__global__ void k_zero_out(float* __restrict__ out, int n) {
  int i = blockIdx.x * blockDim.x + threadIdx.x;
  if (i < n) out[i] = 0.f;
}

// ---------------- dtype prep: x -> bf16, W -> bf16 transposed ----------------

__global__ void k_cvt(const float* __restrict__ x, bf16* __restrict__ xb, long n) {
  long i = (long)blockIdx.x * blockDim.x + threadIdx.x;
  if (i < n) xb[i] = __float2bfloat16(x[i]);
}

// W[K][NN] (f32) -> Wt[NN][K] (bf16)
__global__ void k_tw(const float* __restrict__ W, bf16* __restrict__ Wt, int K, int NN) {
  int i = blockIdx.x * blockDim.x + threadIdx.x;
  if (i >= K * NN) return;
  int k = i / NN, n = i - k * NN;
  Wt[(size_t)n * K + k] = __float2bfloat16(W[i]);
}

// ---------------- preprocessing: counting-sort edges by dst ----------------

__global__ void k_hist(const int* __restrict__ dst, int* __restrict__ deg, int E, int Et) {
  int e = blockIdx.x * blockDim.x + threadIdx.x;
  if (e >= Et) return;
  int d = (e < E) ? dst[e] : (e - E);   // self-loops appended
  atomicAdd(&deg[d], 1);
}

__global__ void k_scan1(const int* __restrict__ deg, int* __restrict__ offs,
                        int* __restrict__ bsum, int n) {
  __shared__ int sd[256];
  int t = threadIdx.x;
  int base = blockIdx.x * 1024 + t * 4;
  int v[4]; int tsum = 0;
#pragma unroll
  for (int i = 0; i < 4; ++i) { v[i] = (base + i < n) ? deg[base + i] : 0; tsum += v[i]; }
  sd[t] = tsum;
  __syncthreads();
  for (int off = 1; off < 256; off <<= 1) {
    int x = (t >= off) ? sd[t - off] : 0;
    __syncthreads();
    sd[t] += x;
    __syncthreads();
  }
  int excl = sd[t] - tsum;
#pragma unroll
  for (int i = 0; i < 4; ++i) { if (base + i < n) offs[base + i] = excl; excl += v[i]; }
  if (t == 255) bsum[blockIdx.x] = sd[255];
}

__global__ void k_scan2(int* bsum, int nb) {
  if (threadIdx.x == 0 && blockIdx.x == 0) {
    int run = 0;
    for (int i = 0; i < nb; ++i) { int t = bsum[i]; bsum[i] = run; run += t; }
  }
}

__global__ void k_scan3(int* __restrict__ offs, const int* __restrict__ bsum, int n, int total) {
  int t = threadIdx.x;
  int base = blockIdx.x * 1024 + t * 4;
  int add = bsum[blockIdx.x];
#pragma unroll
  for (int i = 0; i < 4; ++i) if (base + i < n) offs[base + i] += add;
  if (blockIdx.x == 0 && t == 0) offs[n] = total;
}

__global__ void k_scatter(const int* __restrict__ src, const int* __restrict__ dst,
                          const int* __restrict__ offs, int* __restrict__ cur,
                          int* __restrict__ ssrc, int E, int Et) {
  int e = blockIdx.x * blockDim.x + threadIdx.x;
  if (e >= Et) return;
  int s, d;
  if (e < E) { s = src[e]; d = dst[e]; } else { s = d = e - E; }
  int pos = offs[d] + atomicAdd(&cur[d], 1);
  ssrc[pos] = s;
}

// ---------------- bf16 MFMA GEMM: C[M,NN](bf16) = A[M,K](bf16) @ Wt[NN,K](bf16)^T ----

__global__ __launch_bounds__(256) void k_gemm_mfma(const bf16* __restrict__ A,
                                                   const bf16* __restrict__ Wt,
                                                   bf16* __restrict__ C,
                                                   int K, int NN) {
  __shared__ __align__(16) short sA[64 * 64];   // 8 KB, 64 rows x 64 cols bf16
  int t = threadIdx.x;
  int wv = t >> 6, lane = t & 63;
  int quad = lane >> 4, l15 = lane & 15;
  size_t bm0 = (size_t)blockIdx.x * 64;
  int bn0 = blockIdx.y * 64;
  const bf16* Ab = A + bm0 * K;
  const bf16* Bp = Wt + (size_t)(bn0 + wv * 16 + l15) * K;  // this lane's weight row
  f4v acc[4] = {f4v{0,0,0,0}, f4v{0,0,0,0}, f4v{0,0,0,0}, f4v{0,0,0,0}};

  for (int kb = 0; kb < K; kb += 64) {
#pragma unroll
    for (int j = 0; j < 2; ++j) {
      int idx = j * 256 + t;
      int row = idx >> 3, p = idx & 7;
      int c = p ^ (row & 7);                  // global 16B-chunk landing at pos p
      const bf16* g = Ab + (size_t)row * K + kb + c * 8;
      __builtin_amdgcn_global_load_lds(
          (const __attribute__((address_space(1))) void*)g,
          (__attribute__((address_space(3))) void*)((char*)sA + (size_t)(j * 256 + wv * 64) * 16),
          16, 0, 0);
    }
    __syncthreads();
#pragma unroll
    for (int kk = 0; kk < 2; ++kk) {
      s8v bfrag = *(const s8v*)(Bp + kb + kk * 32 + quad * 8);
#pragma unroll
      for (int ms = 0; ms < 4; ++ms) {
        int row = ms * 16 + l15;
        int pos = (kk * 4 + quad) ^ (row & 7);
        s8v afrag = *(const s8v*)((const char*)sA + (size_t)row * 128 + pos * 16);
        acc[ms] = __builtin_amdgcn_mfma_f32_16x16x32_bf16(afrag, bfrag, acc[ms], 0, 0, 0);
      }
    }
    __syncthreads();
  }
  // C/D layout: col = lane&15, row = quad*4 + reg  [m89/m91 verified]
  int coln = bn0 + wv * 16 + l15;
#pragma unroll
  for (int ms = 0; ms < 4; ++ms)
#pragma unroll
    for (int r = 0; r < 4; ++r)
      C[(bm0 + ms * 16 + quad * 4 + r) * NN + coln] = __float2bfloat16(acc[ms][r]);
}

// ---------------- attention logits al_s/al_d: one wave per node ----------------

__global__ void k_al(const bf16* __restrict__ h, const float* __restrict__ as,
                     const float* __restrict__ ad, float* __restrict__ al_s,
                     float* __restrict__ al_d, int N, int H, int F) {
  int wave = (blockIdx.x * blockDim.x + threadIdx.x) >> 6;
  int lane = threadIdx.x & 63;
  if (wave >= N) return;
  const bf16* hrow = h + (size_t)wave * H * F;
  for (int hd = 0; hd < H; ++hd) {
    float ss = 0.f, sd = 0.f;
    for (int f = lane; f < F; f += 64) {
      float v = __bfloat162float(hrow[hd * F + f]);
      ss += v * as[hd * F + f];
      sd += v * ad[hd * F + f];
    }
#pragma unroll
    for (int off = 32; off; off >>= 1) {
      ss += __shfl_xor(ss, off, 64);
      sd += __shfl_xor(sd, off, 64);
    }
    if (lane == 0) { al_s[wave * H + hd] = ss; al_d[wave * H + hd] = sd; }
  }
}

// ---------------- segment softmax (max + expsum): one wave per node ----------------

__global__ void k_attn(const int* __restrict__ ssrc, const int* __restrict__ offs,
                       const float* __restrict__ al_s, const float* __restrict__ al_d,
                       float* __restrict__ alpha, float* __restrict__ rden, int N, int H) {
  int wave = (blockIdx.x * blockDim.x + threadIdx.x) >> 6;
  int lane = threadIdx.x & 63;
  if (wave >= N) return;
  int start = offs[wave], end = offs[wave + 1];
  float ald[3], mx[3], den[3];
  for (int hd = 0; hd < H; ++hd) { ald[hd] = al_d[wave * H + hd]; mx[hd] = -1e30f; den[hd] = 0.f; }
  for (int pos = start + lane; pos < end; pos += 64) {
    int s = ssrc[pos];
    for (int hd = 0; hd < H; ++hd) {
      float e = lrelu(al_s[s * H + hd] + ald[hd]);
      mx[hd] = fmaxf(mx[hd], e);
    }
  }
  for (int hd = 0; hd < H; ++hd)
#pragma unroll
    for (int off = 32; off; off >>= 1) mx[hd] = fmaxf(mx[hd], __shfl_xor(mx[hd], off, 64));
  for (int pos = start + lane; pos < end; pos += 64) {
    int s = ssrc[pos];
    for (int hd = 0; hd < H; ++hd) {
      float e = lrelu(al_s[s * H + hd] + ald[hd]);
      float ex = __expf(e - mx[hd]);
      alpha[pos * H + hd] = ex;
      den[hd] += ex;
    }
  }
  for (int hd = 0; hd < H; ++hd) {
#pragma unroll
    for (int off = 32; off; off >>= 1) den[hd] += __shfl_xor(den[hd], off, 64);
    if (lane == 0) rden[wave * H + hd] = 1.f / (den[hd] + 1e-16f);
  }
}

// ---------------- weighted aggregation: one wave per node, all heads fused ----------------
// 2-deep edge unroll for memory-level parallelism; lane covers features (lane*2, lane*2+1).

template <int H, typename OT>
__global__ void k_agg(const bf16* __restrict__ hbuf, const int* __restrict__ ssrc,
                      const int* __restrict__ offs, const float* __restrict__ alpha,
                      const float* __restrict__ rden, const float* __restrict__ bias,
                      OT* __restrict__ out, int N) {
  int n = (blockIdx.x * blockDim.x + threadIdx.x) >> 6;
  int lane = threadIdx.x & 63;
  if (n >= N) return;
  int start = offs[n], end = offs[n + 1];
  int f0 = lane * 2;
  float accx[H], accy[H];
#pragma unroll
  for (int hd = 0; hd < H; ++hd) { accx[hd] = 0.f; accy[hd] = 0.f; }

  for (int pos = start; pos < end; pos += 2) {
    int has1 = (pos + 1 < end);
    int p1 = has1 ? pos + 1 : pos;
    int s0 = ssrc[pos];
    int s1 = ssrc[p1];
    const bf16* h0 = hbuf + (size_t)s0 * (H * 128) + f0;
    const bf16* h1 = hbuf + (size_t)s1 * (H * 128) + f0;
    bf16x2 v0[H], v1[H];
#pragma unroll
    for (int hd = 0; hd < H; ++hd) v0[hd] = *(const bf16x2*)(h0 + hd * 128);
#pragma unroll
    for (int hd = 0; hd < H; ++hd) v1[hd] = *(const bf16x2*)(h1 + hd * 128);
    float a0[H], a1[H];
#pragma unroll
    for (int hd = 0; hd < H; ++hd) {
      a0[hd] = alpha[(size_t)pos * H + hd];
      a1[hd] = has1 ? alpha[(size_t)p1 * H + hd] : 0.f;
    }
#pragma unroll
    for (int hd = 0; hd < H; ++hd) {
      float2 f0v = __bfloat1622float2(v0[hd]);
      float2 f1v = __bfloat1622float2(v1[hd]);
      accx[hd] += a0[hd] * f0v.x + a1[hd] * f1v.x;
      accy[hd] += a0[hd] * f0v.y + a1[hd] * f1v.y;
    }
  }
#pragma unroll
  for (int hd = 0; hd < H; ++hd) {
    float r = rden[n * H + hd];
    float ox = lrelu(accx[hd] * r + bias[hd * 128 + f0]);
    float oy = lrelu(accy[hd] * r + bias[hd * 128 + f0 + 1]);
    st2(&out[((size_t)n * H + hd) * 128 + f0], ox, oy);
  }
}

// ---------------- global mean pool (layer-3 out is fp32) ----------------

__global__ void k_pool_acc(const float* __restrict__ h, const int* __restrict__ batch,
                           float* __restrict__ pool, int* __restrict__ cnt, int N) {
  int n = blockIdx.x;
  int t = threadIdx.x;   // 128 threads = feature
  if (n >= N) return;
  int g = batch[n];
  atomicAdd(&pool[g * 128 + t], h[(size_t)n * 128 + t]);
  if (t == 0) atomicAdd(&cnt[g], 1);
}

__global__ void k_pool_div(const float* __restrict__ pool, const int* __restrict__ cnt,
                           float* __restrict__ out, int G) {
  int i = blockIdx.x * blockDim.x + threadIdx.x;
  if (i >= G * 128) return;
  int g = i >> 7;
  float c = (float)max(cnt[g], 1);
  out[i] = pool[i] / c;
}

// ---------------- host launcher ----------------

extern "C" void kernel_launch(void* const* d_in, const int* in_sizes, int n_in,
                              void* d_out, int out_size, void* d_ws, size_t ws_size,
                              hipStream_t stream) {
  const float* x   = (const float*)d_in[0];
  const int*   ei  = (const int*)d_in[1];
  const int*   bat = (const int*)d_in[2];
  const float* W1  = (const float*)d_in[3];
  const float* a1s = (const float*)d_in[4];
  const float* a1d = (const float*)d_in[5];
  const float* b1  = (const float*)d_in[6];
  const float* W2  = (const float*)d_in[7];
  const float* a2s = (const float*)d_in[8];
  const float* a2d = (const float*)d_in[9];
  const float* b2  = (const float*)d_in[10];
  const float* W3  = (const float*)d_in[11];
  const float* a3s = (const float*)d_in[12];
  const float* a3d = (const float*)d_in[13];
  const float* b3  = (const float*)d_in[14];
  float* out = (float*)d_out;

  const int N = in_sizes[2];          // 200000
  const int E = in_sizes[1] / 2;      // 1600000
  const int Et = E + N;               // with self-loops
  const int G = out_size / 128;       // 5000
  const int H = 3;

  // ---- workspace carve (bf16 intermediates) ----
  char* p = (char*)d_ws;
  auto carve = [&](size_t bytes) { void* r = (void*)p; p += (bytes + 255) & ~(size_t)255; return r; };
  bf16*  bufA   = (bf16*)carve((size_t)N * 384 * 2);   // agg out / GEMM A; also hosts xb & fp32 layer-3 out
  bf16*  bufB   = (bf16*)carve((size_t)N * 384 * 2);   // GEMM output h
  float* al_s   = (float*)carve((size_t)N * 3 * 4);
  float* al_d   = (float*)carve((size_t)N * 3 * 4);
  float* rden   = (float*)carve((size_t)N * 3 * 4);
  float* alpha  = (float*)carve((size_t)Et * 3 * 4);
  int*   ssrc   = (int*)carve((size_t)Et * 4);
  int*   offs   = (int*)carve((size_t)(N + 1) * 4);
  int*   deg    = (int*)carve((size_t)N * 4);
  int*   cur    = (int*)carve((size_t)N * 4);
  int*   bsum   = (int*)carve(4096 * 4);
  float* pool   = (float*)carve((size_t)G * 128 * 4);
  int*   cnt    = (int*)carve((size_t)G * 4);
  bf16*  Wt1    = (bf16*)carve((size_t)384 * 128 * 2);
  bf16*  Wt2    = (bf16*)carve((size_t)384 * 384 * 2);
  bf16*  Wt3    = (bf16*)carve((size_t)128 * 384 * 2);
  size_t need = (size_t)(p - (char*)d_ws);

  if (ws_size < need) {
    k_zero_out<<<(out_size + 255) / 256, 256, 0, stream>>>(out, out_size);
    return;
  }

  const int* esrc = ei;
  const int* edst = ei + E;

  int ebl = (Et + 255) / 256;
  int NB = (N + 1023) / 1024;
  int nodeWaveBlocks = (N * 64 + 255) / 256;

  // ---- prep: weight transpose+cast, x cast (xb aliases bufA) ----
  bf16* xb = bufA;
  k_cvt<<<((long)N * 128 + 255) / 256, 256, 0, stream>>>(x, xb, (long)N * 128);
  k_tw<<<(128 * 384 + 255) / 256, 256, 0, stream>>>(W1, Wt1, 128, 384);
  k_tw<<<(384 * 384 + 255) / 256, 256, 0, stream>>>(W2, Wt2, 384, 384);
  k_tw<<<(384 * 128 + 255) / 256, 256, 0, stream>>>(W3, Wt3, 384, 128);

  // ---- sort edges by dst ----
  k_zero<<<(N + 255) / 256, 256, 0, stream>>>((unsigned int*)deg, N);
  k_hist<<<ebl, 256, 0, stream>>>(edst, deg, E, Et);
  k_scan1<<<NB, 256, 0, stream>>>(deg, offs, bsum, N);
  k_scan2<<<1, 64, 0, stream>>>(bsum, NB);
  k_scan3<<<NB, 256, 0, stream>>>(offs, bsum, N, Et);
  k_zero<<<(N + 255) / 256, 256, 0, stream>>>((unsigned int*)cur, N);
  k_scatter<<<ebl, 256, 0, stream>>>(esrc, edst, offs, cur, ssrc, E, Et);

  dim3 g1(N / 64, 6), g2(N / 64, 6), g3(N / 64, 2);

  // ---- layer 1: xb[N,128] @ W1 -> bufB[N,384] ----
  k_gemm_mfma<<<g1, 256, 0, stream>>>(xb, Wt1, bufB, 128, 384);
  k_al<<<nodeWaveBlocks, 256, 0, stream>>>(bufB, a1s, a1d, al_s, al_d, N, H, 128);
  k_attn<<<nodeWaveBlocks, 256, 0, stream>>>(ssrc, offs, al_s, al_d, alpha, rden, N, H);
  k_agg<3, bf16><<<nodeWaveBlocks, 256, 0, stream>>>(bufB, ssrc, offs, alpha, rden, b1, bufA, N);

  // ---- layer 2: bufA[N,384] @ W2 -> bufB[N,384] ----
  k_gemm_mfma<<<g2, 256, 0, stream>>>(bufA, Wt2, bufB, 384, 384);
  k_al<<<nodeWaveBlocks, 256, 0, stream>>>(bufB, a2s, a2d, al_s, al_d, N, H, 128);
  k_attn<<<nodeWaveBlocks, 256, 0, stream>>>(ssrc, offs, al_s, al_d, alpha, rden, N, H);
  k_agg<3, bf16><<<nodeWaveBlocks, 256, 0, stream>>>(bufB, ssrc, offs, alpha, rden, b2, bufA, N);

  // ---- layer 3: bufA[N,384] @ W3 -> bufB[N,128], heads=1, fp32 agg out ----
  k_gemm_mfma<<<g3, 256, 0, stream>>>(bufA, Wt3, bufB, 384, 128);
  k_al<<<nodeWaveBlocks, 256, 0, stream>>>(bufB, a3s, a3d, al_s, al_d, N, 1, 128);
  k_attn<<<nodeWaveBlocks, 256, 0, stream>>>(ssrc, offs, al_s, al_d, alpha, rden, N, 1);
  float* out3 = (float*)bufA;
  k_agg<1, float><<<nodeWaveBlocks, 256, 0, stream>>>(bufB, ssrc, offs, alpha, rden, b3, out3, N);

  // ---- global mean pool ----
  k_zero<<<(G * 128 + 255) / 256, 256, 0, stream>>>((unsigned int*)pool, (long)G * 128);
  k_zero<<<(G + 255) / 256, 256, 0, stream>>>((unsigned int*)cnt, G);
  k_pool_acc<<<N, 128, 0, stream>>>(out3, bat, pool, cnt, N);
  k_pool_div<<<(G * 128 + 255) / 256, 256, 0, stream>>>(pool, cnt, out, G);
}

// Round 5
// 1900.549 us; speedup vs baseline: 1.8617x; 1.1015x over previous
//
#include <hip/hip_runtime.h>
#include <hip/hip_bf16.h>
#include <math.h>

#define LRELU_SLOPE 0.2f
typedef __hip_bfloat16 bf16;
typedef __hip_bfloat162 bf16x2;

typedef short s8v __attribute__((ext_vector_type(8)));   // 8 bf16 (4 VGPRs)
typedef float f4v __attribute__((ext_vector_type(4)));   // MFMA acc

__device__ __forceinline__ float lrelu(float v) { return v > 0.f ? v : LRELU_SLOPE * v; }

__device__ __forceinline__ void st2(bf16* p, float x, float y) {
  float2 f{x, y};
  *(bf16x2*)p = __float22bfloat162_rn(f);
}
__device__ __forceinline__ void st2(float* p, float x, float y) {
  *(float2*)p = float2{x, y};
}

// ---------------- zero helper (avoid hipMemsetAsync in capture) ----------------

__global__ void k_zero(unsigned int* __restrict__ p, long n) {
  long i = (long)blockIdx.x * blockDim.x + threadIdx.x;
  if (i < n) p[i] = 0u;
}

__global__ void k_zero_out(float* __restrict__ out, int n) {
  int i = blockIdx.x * blockDim.x + threadIdx.x;
  if (i < n) out[i] = 0.f;
}

// ---------------- dtype prep: x -> bf16, W -> bf16 transposed ----------------

__global__ void k_cvt(const float* __restrict__ x, bf16* __restrict__ xb, long n) {
  long i = (long)blockIdx.x * blockDim.x + threadIdx.x;
  if (i < n) xb[i] = __float2bfloat16(x[i]);
}

// W[K][NN] (f32) -> Wt[NN][K] (bf16)
__global__ void k_tw(const float* __restrict__ W, bf16* __restrict__ Wt, int K, int NN) {
  int i = blockIdx.x * blockDim.x + threadIdx.x;
  if (i >= K * NN) return;
  int k = i / NN, n = i - k * NN;
  Wt[(size_t)n * K + k] = __float2bfloat16(W[i]);
}

// ---------------- preprocessing: counting-sort edges by dst ----------------

__global__ void k_hist(const int* __restrict__ dst, int* __restrict__ deg, int E, int Et) {
  int e = blockIdx.x * blockDim.x + threadIdx.x;
  if (e >= Et) return;
  int d = (e < E) ? dst[e] : (e - E);   // self-loops appended
  atomicAdd(&deg[d], 1);
}

// also used for graph histogram over batch[]
__global__ void k_hist1(const int* __restrict__ idx, int* __restrict__ deg, int n) {
  int i = blockIdx.x * blockDim.x + threadIdx.x;
  if (i < n) atomicAdd(&deg[idx[i]], 1);
}

__global__ void k_scan1(const int* __restrict__ deg, int* __restrict__ offs,
                        int* __restrict__ bsum, int n) {
  __shared__ int sd[256];
  int t = threadIdx.x;
  int base = blockIdx.x * 1024 + t * 4;
  int v[4]; int tsum = 0;
#pragma unroll
  for (int i = 0; i < 4; ++i) { v[i] = (base + i < n) ? deg[base + i] : 0; tsum += v[i]; }
  sd[t] = tsum;
  __syncthreads();
  for (int off = 1; off < 256; off <<= 1) {
    int x = (t >= off) ? sd[t - off] : 0;
    __syncthreads();
    sd[t] += x;
    __syncthreads();
  }
  int excl = sd[t] - tsum;
#pragma unroll
  for (int i = 0; i < 4; ++i) { if (base + i < n) offs[base + i] = excl; excl += v[i]; }
  if (t == 255) bsum[blockIdx.x] = sd[255];
}

__global__ void k_scan2(int* bsum, int nb) {
  if (threadIdx.x == 0 && blockIdx.x == 0) {
    int run = 0;
    for (int i = 0; i < nb; ++i) { int t = bsum[i]; bsum[i] = run; run += t; }
  }
}

__global__ void k_scan3(int* __restrict__ offs, const int* __restrict__ bsum, int n, int total) {
  int t = threadIdx.x;
  int base = blockIdx.x * 1024 + t * 4;
  int add = bsum[blockIdx.x];
#pragma unroll
  for (int i = 0; i < 4; ++i) if (base + i < n) offs[base + i] += add;
  if (blockIdx.x == 0 && t == 0) offs[n] = total;
}

__global__ void k_scatter(const int* __restrict__ src, const int* __restrict__ dst,
                          const int* __restrict__ offs, int* __restrict__ cur,
                          int* __restrict__ ssrc, int E, int Et) {
  int e = blockIdx.x * blockDim.x + threadIdx.x;
  if (e >= Et) return;
  int s, d;
  if (e < E) { s = src[e]; d = dst[e]; } else { s = d = e - E; }
  int pos = offs[d] + atomicAdd(&cur[d], 1);
  ssrc[pos] = s;
}

// ---------------- bf16 MFMA GEMM: C[M,NN](bf16) = A[M,K](bf16) @ Wt[NN,K](bf16)^T ----

__global__ __launch_bounds__(256) void k_gemm_mfma(const bf16* __restrict__ A,
                                                   const bf16* __restrict__ Wt,
                                                   bf16* __restrict__ C,
                                                   int K, int NN) {
  __shared__ __align__(16) short sA[64 * 64];   // 8 KB, 64 rows x 64 cols bf16
  int t = threadIdx.x;
  int wv = t >> 6, lane = t & 63;
  int quad = lane >> 4, l15 = lane & 15;
  size_t bm0 = (size_t)blockIdx.x * 64;
  int bn0 = blockIdx.y * 64;
  const bf16* Ab = A + bm0 * K;
  const bf16* Bp = Wt + (size_t)(bn0 + wv * 16 + l15) * K;  // this lane's weight row
  f4v acc[4] = {f4v{0,0,0,0}, f4v{0,0,0,0}, f4v{0,0,0,0}, f4v{0,0,0,0}};

  for (int kb = 0; kb < K; kb += 64) {
#pragma unroll
    for (int j = 0; j < 2; ++j) {
      int idx = j * 256 + t;
      int row = idx >> 3, p = idx & 7;
      int c = p ^ (row & 7);                  // global 16B-chunk landing at pos p
      const bf16* g = Ab + (size_t)row * K + kb + c * 8;
      __builtin_amdgcn_global_load_lds(
          (const __attribute__((address_space(1))) void*)g,
          (__attribute__((address_space(3))) void*)((char*)sA + (size_t)(j * 256 + wv * 64) * 16),
          16, 0, 0);
    }
    __syncthreads();
#pragma unroll
    for (int kk = 0; kk < 2; ++kk) {
      s8v bfrag = *(const s8v*)(Bp + kb + kk * 32 + quad * 8);
#pragma unroll
      for (int ms = 0; ms < 4; ++ms) {
        int row = ms * 16 + l15;
        int pos = (kk * 4 + quad) ^ (row & 7);
        s8v afrag = *(const s8v*)((const char*)sA + (size_t)row * 128 + pos * 16);
        acc[ms] = __builtin_amdgcn_mfma_f32_16x16x32_bf16(afrag, bfrag, acc[ms], 0, 0, 0);
      }
    }
    __syncthreads();
  }
  // C/D layout: col = lane&15, row = quad*4 + reg  [m89/m91 verified]
  int coln = bn0 + wv * 16 + l15;
#pragma unroll
  for (int ms = 0; ms < 4; ++ms)
#pragma unroll
    for (int r = 0; r < 4; ++r)
      C[(bm0 + ms * 16 + quad * 4 + r) * NN + coln] = __float2bfloat16(acc[ms][r]);
}

// ---------------- attention logits al_s/al_d: one wave per node ----------------

__global__ void k_al(const bf16* __restrict__ h, const float* __restrict__ as,
                     const float* __restrict__ ad, float* __restrict__ al_s,
                     float* __restrict__ al_d, int N, int H, int F) {
  int wave = (blockIdx.x * blockDim.x + threadIdx.x) >> 6;
  int lane = threadIdx.x & 63;
  if (wave >= N) return;
  const bf16* hrow = h + (size_t)wave * H * F;
  for (int hd = 0; hd < H; ++hd) {
    float ss = 0.f, sd = 0.f;
    for (int f = lane; f < F; f += 64) {
      float v = __bfloat162float(hrow[hd * F + f]);
      ss += v * as[hd * F + f];
      sd += v * ad[hd * F + f];
    }
#pragma unroll
    for (int off = 32; off; off >>= 1) {
      ss += __shfl_xor(ss, off, 64);
      sd += __shfl_xor(sd, off, 64);
    }
    if (lane == 0) { al_s[wave * H + hd] = ss; al_d[wave * H + hd] = sd; }
  }
}

// ---------------- segment softmax (max + expsum): one wave per node ----------------

__global__ void k_attn(const int* __restrict__ ssrc, const int* __restrict__ offs,
                       const float* __restrict__ al_s, const float* __restrict__ al_d,
                       float* __restrict__ alpha, float* __restrict__ rden, int N, int H) {
  int wave = (blockIdx.x * blockDim.x + threadIdx.x) >> 6;
  int lane = threadIdx.x & 63;
  if (wave >= N) return;
  int start = offs[wave], end = offs[wave + 1];
  float ald[3], mx[3], den[3];
  for (int hd = 0; hd < H; ++hd) { ald[hd] = al_d[wave * H + hd]; mx[hd] = -1e30f; den[hd] = 0.f; }
  for (int pos = start + lane; pos < end; pos += 64) {
    int s = ssrc[pos];
    for (int hd = 0; hd < H; ++hd) {
      float e = lrelu(al_s[s * H + hd] + ald[hd]);
      mx[hd] = fmaxf(mx[hd], e);
    }
  }
  for (int hd = 0; hd < H; ++hd)
#pragma unroll
    for (int off = 32; off; off >>= 1) mx[hd] = fmaxf(mx[hd], __shfl_xor(mx[hd], off, 64));
  for (int pos = start + lane; pos < end; pos += 64) {
    int s = ssrc[pos];
    for (int hd = 0; hd < H; ++hd) {
      float e = lrelu(al_s[s * H + hd] + ald[hd]);
      float ex = __expf(e - mx[hd]);
      alpha[pos * H + hd] = ex;
      den[hd] += ex;
    }
  }
  for (int hd = 0; hd < H; ++hd) {
#pragma unroll
    for (int off = 32; off; off >>= 1) den[hd] += __shfl_xor(den[hd], off, 64);
    if (lane == 0) rden[wave * H + hd] = 1.f / (den[hd] + 1e-16f);
  }
}

// ---------------- weighted aggregation: one wave per node, all heads fused ----------------
// 4-deep edge unroll for memory-level parallelism; lane covers features (lane*2, lane*2+1).

template <int H, typename OT>
__global__ void k_agg(const bf16* __restrict__ hbuf, const int* __restrict__ ssrc,
                      const int* __restrict__ offs, const float* __restrict__ alpha,
                      const float* __restrict__ rden, const float* __restrict__ bias,
                      OT* __restrict__ out, int N) {
  int n = (blockIdx.x * blockDim.x + threadIdx.x) >> 6;
  int lane = threadIdx.x & 63;
  if (n >= N) return;
  int start = offs[n], end = offs[n + 1];
  int f0 = lane * 2;
  float accx[H], accy[H];
#pragma unroll
  for (int hd = 0; hd < H; ++hd) { accx[hd] = 0.f; accy[hd] = 0.f; }

  for (int pos = start; pos < end; pos += 4) {
    int pp[4], valid[4];
#pragma unroll
    for (int u = 0; u < 4; ++u) {
      int q = pos + u;
      valid[u] = (q < end);
      pp[u] = valid[u] ? q : pos;
    }
    int s[4];
#pragma unroll
    for (int u = 0; u < 4; ++u) s[u] = ssrc[pp[u]];
    bf16x2 v[4][H];
#pragma unroll
    for (int u = 0; u < 4; ++u) {
      const bf16* hp = hbuf + (size_t)s[u] * (H * 128) + f0;
#pragma unroll
      for (int hd = 0; hd < H; ++hd) v[u][hd] = *(const bf16x2*)(hp + hd * 128);
    }
    float a[4][H];
#pragma unroll
    for (int u = 0; u < 4; ++u)
#pragma unroll
      for (int hd = 0; hd < H; ++hd)
        a[u][hd] = valid[u] ? alpha[(size_t)pp[u] * H + hd] : 0.f;
#pragma unroll
    for (int u = 0; u < 4; ++u)
#pragma unroll
      for (int hd = 0; hd < H; ++hd) {
        float2 f = __bfloat1622float2(v[u][hd]);
        accx[hd] += a[u][hd] * f.x;
        accy[hd] += a[u][hd] * f.y;
      }
  }
#pragma unroll
  for (int hd = 0; hd < H; ++hd) {
    float r = rden[n * H + hd];
    float ox = lrelu(accx[hd] * r + bias[hd * 128 + f0]);
    float oy = lrelu(accy[hd] * r + bias[hd * 128 + f0 + 1]);
    st2(&out[((size_t)n * H + hd) * 128 + f0], ox, oy);
  }
}

// ---------------- global mean pool: one wave per graph, no atomics ----------------
// batch is sorted; goffs[g]..goffs[g+1] is graph g's node range.

__global__ void k_pool(const float* __restrict__ h, const int* __restrict__ goffs,
                       float* __restrict__ out, int G) {
  int g = (blockIdx.x * blockDim.x + threadIdx.x) >> 6;
  int lane = threadIdx.x & 63;
  if (g >= G) return;
  int s = goffs[g], e = goffs[g + 1];
  float ax = 0.f, ay = 0.f;
  for (int n = s; n < e; ++n) {
    float2 v = *(const float2*)&h[(size_t)n * 128 + lane * 2];
    ax += v.x; ay += v.y;
  }
  float c = fmaxf((float)(e - s), 1.f);
  st2(&out[(size_t)g * 128 + lane * 2], ax / c, ay / c);
}

// ---------------- host launcher ----------------

extern "C" void kernel_launch(void* const* d_in, const int* in_sizes, int n_in,
                              void* d_out, int out_size, void* d_ws, size_t ws_size,
                              hipStream_t stream) {
  const float* x   = (const float*)d_in[0];
  const int*   ei  = (const int*)d_in[1];
  const int*   bat = (const int*)d_in[2];
  const float* W1  = (const float*)d_in[3];
  const float* a1s = (const float*)d_in[4];
  const float* a1d = (const float*)d_in[5];
  const float* b1  = (const float*)d_in[6];
  const float* W2  = (const float*)d_in[7];
  const float* a2s = (const float*)d_in[8];
  const float* a2d = (const float*)d_in[9];
  const float* b2  = (const float*)d_in[10];
  const float* W3  = (const float*)d_in[11];
  const float* a3s = (const float*)d_in[12];
  const float* a3d = (const float*)d_in[13];
  const float* b3  = (const float*)d_in[14];
  float* out = (float*)d_out;

  const int N = in_sizes[2];          // 200000
  const int E = in_sizes[1] / 2;      // 1600000
  const int Et = E + N;               // with self-loops
  const int G = out_size / 128;       // 5000
  const int H = 3;

  // ---- workspace carve (bf16 intermediates) ----
  char* p = (char*)d_ws;
  auto carve = [&](size_t bytes) { void* r = (void*)p; p += (bytes + 255) & ~(size_t)255; return r; };
  bf16*  bufA   = (bf16*)carve((size_t)N * 384 * 2);   // agg out / GEMM A; also hosts xb & fp32 layer-3 out
  bf16*  bufB   = (bf16*)carve((size_t)N * 384 * 2);   // GEMM output h
  float* al_s   = (float*)carve((size_t)N * 3 * 4);
  float* al_d   = (float*)carve((size_t)N * 3 * 4);
  float* rden   = (float*)carve((size_t)N * 3 * 4);
  float* alpha  = (float*)carve((size_t)Et * 3 * 4);
  int*   ssrc   = (int*)carve((size_t)Et * 4);
  int*   offs   = (int*)carve((size_t)(N + 1) * 4);
  int*   deg    = (int*)carve((size_t)N * 4);
  int*   cur    = (int*)carve((size_t)N * 4);
  int*   bsum   = (int*)carve(4096 * 4);
  int*   gdeg   = (int*)carve((size_t)G * 4);
  int*   goffs  = (int*)carve((size_t)(G + 1) * 4);
  bf16*  Wt1    = (bf16*)carve((size_t)384 * 128 * 2);
  bf16*  Wt2    = (bf16*)carve((size_t)384 * 384 * 2);
  bf16*  Wt3    = (bf16*)carve((size_t)128 * 384 * 2);
  size_t need = (size_t)(p - (char*)d_ws);

  if (ws_size < need) {
    k_zero_out<<<(out_size + 255) / 256, 256, 0, stream>>>(out, out_size);
    return;
  }

  const int* esrc = ei;
  const int* edst = ei + E;

  int ebl = (Et + 255) / 256;
  int NB = (N + 1023) / 1024;
  int GB = (G + 1023) / 1024;
  int nodeWaveBlocks = (N * 64 + 255) / 256;

  // ---- prep: weight transpose+cast, x cast (xb aliases bufA) ----
  bf16* xb = bufA;
  k_cvt<<<((long)N * 128 + 255) / 256, 256, 0, stream>>>(x, xb, (long)N * 128);
  k_tw<<<(128 * 384 + 255) / 256, 256, 0, stream>>>(W1, Wt1, 128, 384);
  k_tw<<<(384 * 384 + 255) / 256, 256, 0, stream>>>(W2, Wt2, 384, 384);
  k_tw<<<(384 * 128 + 255) / 256, 256, 0, stream>>>(W3, Wt3, 384, 128);

  // ---- sort edges by dst ----
  k_zero<<<(N + 255) / 256, 256, 0, stream>>>((unsigned int*)deg, N);
  k_hist<<<ebl, 256, 0, stream>>>(edst, deg, E, Et);
  k_scan1<<<NB, 256, 0, stream>>>(deg, offs, bsum, N);
  k_scan2<<<1, 64, 0, stream>>>(bsum, NB);
  k_scan3<<<NB, 256, 0, stream>>>(offs, bsum, N, Et);
  k_zero<<<(N + 255) / 256, 256, 0, stream>>>((unsigned int*)cur, N);
  k_scatter<<<ebl, 256, 0, stream>>>(esrc, edst, offs, cur, ssrc, E, Et);

  // ---- graph offsets for pool (batch is sorted) ----
  k_zero<<<(G + 255) / 256, 256, 0, stream>>>((unsigned int*)gdeg, G);
  k_hist1<<<(N + 255) / 256, 256, 0, stream>>>(bat, gdeg, N);
  k_scan1<<<GB, 256, 0, stream>>>(gdeg, goffs, bsum, G);
  k_scan2<<<1, 64, 0, stream>>>(bsum, GB);
  k_scan3<<<GB, 256, 0, stream>>>(goffs, bsum, G, N);

  dim3 g1(N / 64, 6), g2(N / 64, 6), g3(N / 64, 2);

  // ---- layer 1: xb[N,128] @ W1 -> bufB[N,384] ----
  k_gemm_mfma<<<g1, 256, 0, stream>>>(xb, Wt1, bufB, 128, 384);
  k_al<<<nodeWaveBlocks, 256, 0, stream>>>(bufB, a1s, a1d, al_s, al_d, N, H, 128);
  k_attn<<<nodeWaveBlocks, 256, 0, stream>>>(ssrc, offs, al_s, al_d, alpha, rden, N, H);
  k_agg<3, bf16><<<nodeWaveBlocks, 256, 0, stream>>>(bufB, ssrc, offs, alpha, rden, b1, bufA, N);

  // ---- layer 2: bufA[N,384] @ W2 -> bufB[N,384] ----
  k_gemm_mfma<<<g2, 256, 0, stream>>>(bufA, Wt2, bufB, 384, 384);
  k_al<<<nodeWaveBlocks, 256, 0, stream>>>(bufB, a2s, a2d, al_s, al_d, N, H, 128);
  k_attn<<<nodeWaveBlocks, 256, 0, stream>>>(ssrc, offs, al_s, al_d, alpha, rden, N, H);
  k_agg<3, bf16><<<nodeWaveBlocks, 256, 0, stream>>>(bufB, ssrc, offs, alpha, rden, b2, bufA, N);

  // ---- layer 3: bufA[N,384] @ W3 -> bufB[N,128], heads=1, fp32 agg out ----
  k_gemm_mfma<<<g3, 256, 0, stream>>>(bufA, Wt3, bufB, 384, 128);
  k_al<<<nodeWaveBlocks, 256, 0, stream>>>(bufB, a3s, a3d, al_s, al_d, N, 1, 128);
  k_attn<<<nodeWaveBlocks, 256, 0, stream>>>(ssrc, offs, al_s, al_d, alpha, rden, N, 1);
  float* out3 = (float*)bufA;
  k_agg<1, float><<<nodeWaveBlocks, 256, 0, stream>>>(bufB, ssrc, offs, alpha, rden, b3, out3, N);

  // ---- global mean pool: segmented, atomic-free ----
  k_pool<<<(G * 64 + 255) / 256, 256, 0, stream>>>(out3, goffs, out, G);
}

// Round 6
// 1604.254 us; speedup vs baseline: 2.2056x; 1.1847x over previous
//
#include <hip/hip_runtime.h>
#include <hip/hip_bf16.h>
#include <math.h>

#define LRELU_SLOPE 0.2f
typedef __hip_bfloat16 bf16;
typedef __hip_bfloat162 bf16x2;

typedef short s8v __attribute__((ext_vector_type(8)));   // 8 bf16 (4 VGPRs)
typedef float f4v __attribute__((ext_vector_type(4)));   // MFMA acc

__device__ __forceinline__ float lrelu(float v) { return v > 0.f ? v : LRELU_SLOPE * v; }

__device__ __forceinline__ void st2(bf16* p, float x, float y) {
  float2 f{x, y};
  *(bf16x2*)p = __float22bfloat162_rn(f);
}
__device__ __forceinline__ void st2(float* p, float x, float y) {
  *(float2*)p = float2{x, y};
}

// nontemporal variants: bypass L2/L3 so streaming output doesn't evict the h gather set
__device__ __forceinline__ void st2_nt(bf16* p, float x, float y) {
  float2 f{x, y};
  bf16x2 v = __float22bfloat162_rn(f);
  __builtin_nontemporal_store(*(unsigned int*)&v, (unsigned int*)p);
}
__device__ __forceinline__ void st2_nt(float* p, float x, float y) {
  __builtin_nontemporal_store(x, p);
  __builtin_nontemporal_store(y, p + 1);
}

// ---------------- zero helper (avoid hipMemsetAsync in capture) ----------------

__global__ void k_zero(unsigned int* __restrict__ p, long n) {
  long i = (long)blockIdx.x * blockDim.x + threadIdx.x;
  if (i < n) p[i] = 0u;
}

__global__ void k_zero_out(float* __restrict__ out, int n) {
  int i = blockIdx.x * blockDim.x + threadIdx.x;
  if (i < n) out[i] = 0.f;
}

// ---------------- dtype prep: x -> bf16, W -> bf16 transposed ----------------

__global__ void k_cvt(const float* __restrict__ x, bf16* __restrict__ xb, long n) {
  long i = (long)blockIdx.x * blockDim.x + threadIdx.x;
  if (i < n) xb[i] = __float2bfloat16(x[i]);
}

// W[K][NN] (f32) -> Wt[NN][K] (bf16)
__global__ void k_tw(const float* __restrict__ W, bf16* __restrict__ Wt, int K, int NN) {
  int i = blockIdx.x * blockDim.x + threadIdx.x;
  if (i >= K * NN) return;
  int k = i / NN, n = i - k * NN;
  Wt[(size_t)n * K + k] = __float2bfloat16(W[i]);
}

// ---------------- preprocessing: counting-sort edges by dst ----------------

__global__ void k_hist(const int* __restrict__ dst, int* __restrict__ deg, int E, int Et) {
  int e = blockIdx.x * blockDim.x + threadIdx.x;
  if (e >= Et) return;
  int d = (e < E) ? dst[e] : (e - E);   // self-loops appended
  atomicAdd(&deg[d], 1);
}

// also used for graph histogram over batch[]
__global__ void k_hist1(const int* __restrict__ idx, int* __restrict__ deg, int n) {
  int i = blockIdx.x * blockDim.x + threadIdx.x;
  if (i < n) atomicAdd(&deg[idx[i]], 1);
}

__global__ void k_scan1(const int* __restrict__ deg, int* __restrict__ offs,
                        int* __restrict__ bsum, int n) {
  __shared__ int sd[256];
  int t = threadIdx.x;
  int base = blockIdx.x * 1024 + t * 4;
  int v[4]; int tsum = 0;
#pragma unroll
  for (int i = 0; i < 4; ++i) { v[i] = (base + i < n) ? deg[base + i] : 0; tsum += v[i]; }
  sd[t] = tsum;
  __syncthreads();
  for (int off = 1; off < 256; off <<= 1) {
    int x = (t >= off) ? sd[t - off] : 0;
    __syncthreads();
    sd[t] += x;
    __syncthreads();
  }
  int excl = sd[t] - tsum;
#pragma unroll
  for (int i = 0; i < 4; ++i) { if (base + i < n) offs[base + i] = excl; excl += v[i]; }
  if (t == 255) bsum[blockIdx.x] = sd[255];
}

__global__ void k_scan2(int* bsum, int nb) {
  if (threadIdx.x == 0 && blockIdx.x == 0) {
    int run = 0;
    for (int i = 0; i < nb; ++i) { int t = bsum[i]; bsum[i] = run; run += t; }
  }
}

__global__ void k_scan3(int* __restrict__ offs, const int* __restrict__ bsum, int n, int total) {
  int t = threadIdx.x;
  int base = blockIdx.x * 1024 + t * 4;
  int add = bsum[blockIdx.x];
#pragma unroll
  for (int i = 0; i < 4; ++i) if (base + i < n) offs[base + i] += add;
  if (blockIdx.x == 0 && t == 0) offs[n] = total;
}

__global__ void k_scatter(const int* __restrict__ src, const int* __restrict__ dst,
                          const int* __restrict__ offs, int* __restrict__ cur,
                          int* __restrict__ ssrc, int E, int Et) {
  int e = blockIdx.x * blockDim.x + threadIdx.x;
  if (e >= Et) return;
  int s, d;
  if (e < E) { s = src[e]; d = dst[e]; } else { s = d = e - E; }
  int pos = offs[d] + atomicAdd(&cur[d], 1);
  ssrc[pos] = s;
}

// ---------------- bf16 MFMA GEMM: C[M,NN](bf16) = A[M,K](bf16) @ Wt[NN,K](bf16)^T ----

__global__ __launch_bounds__(256) void k_gemm_mfma(const bf16* __restrict__ A,
                                                   const bf16* __restrict__ Wt,
                                                   bf16* __restrict__ C,
                                                   int K, int NN) {
  __shared__ __align__(16) short sA[64 * 64];   // 8 KB, 64 rows x 64 cols bf16
  int t = threadIdx.x;
  int wv = t >> 6, lane = t & 63;
  int quad = lane >> 4, l15 = lane & 15;
  size_t bm0 = (size_t)blockIdx.x * 64;
  int bn0 = blockIdx.y * 64;
  const bf16* Ab = A + bm0 * K;
  const bf16* Bp = Wt + (size_t)(bn0 + wv * 16 + l15) * K;  // this lane's weight row
  f4v acc[4] = {f4v{0,0,0,0}, f4v{0,0,0,0}, f4v{0,0,0,0}, f4v{0,0,0,0}};

  for (int kb = 0; kb < K; kb += 64) {
#pragma unroll
    for (int j = 0; j < 2; ++j) {
      int idx = j * 256 + t;
      int row = idx >> 3, p = idx & 7;
      int c = p ^ (row & 7);                  // global 16B-chunk landing at pos p
      const bf16* g = Ab + (size_t)row * K + kb + c * 8;
      __builtin_amdgcn_global_load_lds(
          (const __attribute__((address_space(1))) void*)g,
          (__attribute__((address_space(3))) void*)((char*)sA + (size_t)(j * 256 + wv * 64) * 16),
          16, 0, 0);
    }
    __syncthreads();
#pragma unroll
    for (int kk = 0; kk < 2; ++kk) {
      s8v bfrag = *(const s8v*)(Bp + kb + kk * 32 + quad * 8);
#pragma unroll
      for (int ms = 0; ms < 4; ++ms) {
        int row = ms * 16 + l15;
        int pos = (kk * 4 + quad) ^ (row & 7);
        s8v afrag = *(const s8v*)((const char*)sA + (size_t)row * 128 + pos * 16);
        acc[ms] = __builtin_amdgcn_mfma_f32_16x16x32_bf16(afrag, bfrag, acc[ms], 0, 0, 0);
      }
    }
    __syncthreads();
  }
  // C/D layout: col = lane&15, row = quad*4 + reg  [m89/m91 verified]
  int coln = bn0 + wv * 16 + l15;
#pragma unroll
  for (int ms = 0; ms < 4; ++ms)
#pragma unroll
    for (int r = 0; r < 4; ++r)
      C[(bm0 + ms * 16 + quad * 4 + r) * NN + coln] = __float2bfloat16(acc[ms][r]);
}

// ---------------- attention logits al_s/al_d: one wave per node ----------------

__global__ void k_al(const bf16* __restrict__ h, const float* __restrict__ as,
                     const float* __restrict__ ad, float* __restrict__ al_s,
                     float* __restrict__ al_d, int N, int H, int F) {
  int wave = (blockIdx.x * blockDim.x + threadIdx.x) >> 6;
  int lane = threadIdx.x & 63;
  if (wave >= N) return;
  const bf16* hrow = h + (size_t)wave * H * F;
  for (int hd = 0; hd < H; ++hd) {
    float ss = 0.f, sd = 0.f;
    for (int f = lane; f < F; f += 64) {
      float v = __bfloat162float(hrow[hd * F + f]);
      ss += v * as[hd * F + f];
      sd += v * ad[hd * F + f];
    }
#pragma unroll
    for (int off = 32; off; off >>= 1) {
      ss += __shfl_xor(ss, off, 64);
      sd += __shfl_xor(sd, off, 64);
    }
    if (lane == 0) { al_s[wave * H + hd] = ss; al_d[wave * H + hd] = sd; }
  }
}

// -------- fused segment-softmax + weighted aggregation: one wave per node --------
// Pass 1: lane-parallel max over incoming edges.
// Pass 2: serial 4-deep edge loop; all lanes redundantly compute alpha from broadcast
// al_s loads (L2-hot) + exp, accumulate den in-register (identical across lanes, no
// reduce) and Sum(ex * h[src]) simultaneously. Final: out = lrelu(acc/den + bias).

template <int H, typename OT>
__global__ void k_attn_agg(const bf16* __restrict__ hbuf, const int* __restrict__ ssrc,
                           const int* __restrict__ offs, const float* __restrict__ al_s,
                           const float* __restrict__ al_d, const float* __restrict__ bias,
                           OT* __restrict__ out, int N) {
  int n = (blockIdx.x * blockDim.x + threadIdx.x) >> 6;
  int lane = threadIdx.x & 63;
  if (n >= N) return;
  int start = offs[n], end = offs[n + 1];
  float ald[H], mx[H];
#pragma unroll
  for (int hd = 0; hd < H; ++hd) { ald[hd] = al_d[n * H + hd]; mx[hd] = -1e30f; }

  // pass 1: lane-parallel max
  for (int pos = start + lane; pos < end; pos += 64) {
    int s = ssrc[pos];
#pragma unroll
    for (int hd = 0; hd < H; ++hd)
      mx[hd] = fmaxf(mx[hd], lrelu(al_s[s * H + hd] + ald[hd]));
  }
#pragma unroll
  for (int hd = 0; hd < H; ++hd)
#pragma unroll
    for (int off = 32; off; off >>= 1) mx[hd] = fmaxf(mx[hd], __shfl_xor(mx[hd], off, 64));

  // pass 2: serial edges, 4-deep unroll
  int f0 = lane * 2;
  float den[H], accx[H], accy[H];
#pragma unroll
  for (int hd = 0; hd < H; ++hd) { den[hd] = 0.f; accx[hd] = 0.f; accy[hd] = 0.f; }

  for (int pos = start; pos < end; pos += 4) {
    int pp[4], valid[4], s[4];
#pragma unroll
    for (int u = 0; u < 4; ++u) {
      int q = pos + u;
      valid[u] = (q < end);
      pp[u] = valid[u] ? q : pos;
    }
#pragma unroll
    for (int u = 0; u < 4; ++u) s[u] = ssrc[pp[u]];
    // kick off the long-latency h gathers first
    bf16x2 v[4][H];
#pragma unroll
    for (int u = 0; u < 4; ++u) {
      const bf16* hp = hbuf + (size_t)s[u] * (H * 128) + f0;
#pragma unroll
      for (int hd = 0; hd < H; ++hd) v[u][hd] = *(const bf16x2*)(hp + hd * 128);
    }
    // alpha from broadcast al_s loads (L2-hot) while gathers are in flight
    float a[4][H];
#pragma unroll
    for (int u = 0; u < 4; ++u)
#pragma unroll
      for (int hd = 0; hd < H; ++hd) {
        float e = lrelu(al_s[s[u] * H + hd] + ald[hd]);
        float ex = __expf(e - mx[hd]);
        a[u][hd] = valid[u] ? ex : 0.f;
        den[hd] += a[u][hd];
      }
#pragma unroll
    for (int u = 0; u < 4; ++u)
#pragma unroll
      for (int hd = 0; hd < H; ++hd) {
        float2 f = __bfloat1622float2(v[u][hd]);
        accx[hd] += a[u][hd] * f.x;
        accy[hd] += a[u][hd] * f.y;
      }
  }
#pragma unroll
  for (int hd = 0; hd < H; ++hd) {
    float r = 1.f / (den[hd] + 1e-16f);
    float ox = lrelu(accx[hd] * r + bias[hd * 128 + f0]);
    float oy = lrelu(accy[hd] * r + bias[hd * 128 + f0 + 1]);
    st2_nt(&out[((size_t)n * H + hd) * 128 + f0], ox, oy);
  }
}

// ---------------- global mean pool: one wave per graph, no atomics ----------------

__global__ void k_pool(const float* __restrict__ h, const int* __restrict__ goffs,
                       float* __restrict__ out, int G) {
  int g = (blockIdx.x * blockDim.x + threadIdx.x) >> 6;
  int lane = threadIdx.x & 63;
  if (g >= G) return;
  int s = goffs[g], e = goffs[g + 1];
  float ax = 0.f, ay = 0.f;
  for (int n = s; n < e; ++n) {
    float2 v = *(const float2*)&h[(size_t)n * 128 + lane * 2];
    ax += v.x; ay += v.y;
  }
  float c = fmaxf((float)(e - s), 1.f);
  st2(&out[(size_t)g * 128 + lane * 2], ax / c, ay / c);
}

// ---------------- host launcher ----------------

extern "C" void kernel_launch(void* const* d_in, const int* in_sizes, int n_in,
                              void* d_out, int out_size, void* d_ws, size_t ws_size,
                              hipStream_t stream) {
  const float* x   = (const float*)d_in[0];
  const int*   ei  = (const int*)d_in[1];
  const int*   bat = (const int*)d_in[2];
  const float* W1  = (const float*)d_in[3];
  const float* a1s = (const float*)d_in[4];
  const float* a1d = (const float*)d_in[5];
  const float* b1  = (const float*)d_in[6];
  const float* W2  = (const float*)d_in[7];
  const float* a2s = (const float*)d_in[8];
  const float* a2d = (const float*)d_in[9];
  const float* b2  = (const float*)d_in[10];
  const float* W3  = (const float*)d_in[11];
  const float* a3s = (const float*)d_in[12];
  const float* a3d = (const float*)d_in[13];
  const float* b3  = (const float*)d_in[14];
  float* out = (float*)d_out;

  const int N = in_sizes[2];          // 200000
  const int E = in_sizes[1] / 2;      // 1600000
  const int Et = E + N;               // with self-loops
  const int G = out_size / 128;       // 5000
  const int H = 3;

  // ---- workspace carve (bf16 intermediates) ----
  char* p = (char*)d_ws;
  auto carve = [&](size_t bytes) { void* r = (void*)p; p += (bytes + 255) & ~(size_t)255; return r; };
  bf16*  bufA   = (bf16*)carve((size_t)N * 384 * 2);   // agg out / GEMM A; also hosts xb & fp32 layer-3 out
  bf16*  bufB   = (bf16*)carve((size_t)N * 384 * 2);   // GEMM output h
  float* al_s   = (float*)carve((size_t)N * 3 * 4);
  float* al_d   = (float*)carve((size_t)N * 3 * 4);
  int*   ssrc   = (int*)carve((size_t)Et * 4);
  int*   offs   = (int*)carve((size_t)(N + 1) * 4);
  int*   deg    = (int*)carve((size_t)N * 4);
  int*   cur    = (int*)carve((size_t)N * 4);
  int*   bsum   = (int*)carve(4096 * 4);
  int*   gdeg   = (int*)carve((size_t)G * 4);
  int*   goffs  = (int*)carve((size_t)(G + 1) * 4);
  bf16*  Wt1    = (bf16*)carve((size_t)384 * 128 * 2);
  bf16*  Wt2    = (bf16*)carve((size_t)384 * 384 * 2);
  bf16*  Wt3    = (bf16*)carve((size_t)128 * 384 * 2);
  size_t need = (size_t)(p - (char*)d_ws);

  if (ws_size < need) {
    k_zero_out<<<(out_size + 255) / 256, 256, 0, stream>>>(out, out_size);
    return;
  }

  const int* esrc = ei;
  const int* edst = ei + E;

  int ebl = (Et + 255) / 256;
  int NB = (N + 1023) / 1024;
  int GB = (G + 1023) / 1024;
  int nodeWaveBlocks = (N * 64 + 255) / 256;

  // ---- prep: weight transpose+cast, x cast (xb aliases bufA) ----
  bf16* xb = bufA;
  k_cvt<<<((long)N * 128 + 255) / 256, 256, 0, stream>>>(x, xb, (long)N * 128);
  k_tw<<<(128 * 384 + 255) / 256, 256, 0, stream>>>(W1, Wt1, 128, 384);
  k_tw<<<(384 * 384 + 255) / 256, 256, 0, stream>>>(W2, Wt2, 384, 384);
  k_tw<<<(384 * 128 + 255) / 256, 256, 0, stream>>>(W3, Wt3, 384, 128);

  // ---- sort edges by dst ----
  k_zero<<<(N + 255) / 256, 256, 0, stream>>>((unsigned int*)deg, N);
  k_hist<<<ebl, 256, 0, stream>>>(edst, deg, E, Et);
  k_scan1<<<NB, 256, 0, stream>>>(deg, offs, bsum, N);
  k_scan2<<<1, 64, 0, stream>>>(bsum, NB);
  k_scan3<<<NB, 256, 0, stream>>>(offs, bsum, N, Et);
  k_zero<<<(N + 255) / 256, 256, 0, stream>>>((unsigned int*)cur, N);
  k_scatter<<<ebl, 256, 0, stream>>>(esrc, edst, offs, cur, ssrc, E, Et);

  // ---- graph offsets for pool (batch is sorted) ----
  k_zero<<<(G + 255) / 256, 256, 0, stream>>>((unsigned int*)gdeg, G);
  k_hist1<<<(N + 255) / 256, 256, 0, stream>>>(bat, gdeg, N);
  k_scan1<<<GB, 256, 0, stream>>>(gdeg, goffs, bsum, G);
  k_scan2<<<1, 64, 0, stream>>>(bsum, GB);
  k_scan3<<<GB, 256, 0, stream>>>(goffs, bsum, G, N);

  dim3 g1(N / 64, 6), g2(N / 64, 6), g3(N / 64, 2);

  // ---- layer 1: xb[N,128] @ W1 -> bufB[N,384] ----
  k_gemm_mfma<<<g1, 256, 0, stream>>>(xb, Wt1, bufB, 128, 384);
  k_al<<<nodeWaveBlocks, 256, 0, stream>>>(bufB, a1s, a1d, al_s, al_d, N, H, 128);
  k_attn_agg<3, bf16><<<nodeWaveBlocks, 256, 0, stream>>>(bufB, ssrc, offs, al_s, al_d, b1, bufA, N);

  // ---- layer 2: bufA[N,384] @ W2 -> bufB[N,384] ----
  k_gemm_mfma<<<g2, 256, 0, stream>>>(bufA, Wt2, bufB, 384, 384);
  k_al<<<nodeWaveBlocks, 256, 0, stream>>>(bufB, a2s, a2d, al_s, al_d, N, H, 128);
  k_attn_agg<3, bf16><<<nodeWaveBlocks, 256, 0, stream>>>(bufB, ssrc, offs, al_s, al_d, b2, bufA, N);

  // ---- layer 3: bufA[N,384] @ W3 -> bufB[N,128], heads=1, fp32 agg out ----
  k_gemm_mfma<<<g3, 256, 0, stream>>>(bufA, Wt3, bufB, 384, 128);
  k_al<<<nodeWaveBlocks, 256, 0, stream>>>(bufB, a3s, a3d, al_s, al_d, N, 1, 128);
  float* out3 = (float*)bufA;
  k_attn_agg<1, float><<<nodeWaveBlocks, 256, 0, stream>>>(bufB, ssrc, offs, al_s, al_d, b3, out3, N);

  // ---- global mean pool: segmented, atomic-free ----
  k_pool<<<(G * 64 + 255) / 256, 256, 0, stream>>>(out3, goffs, out, G);
}